// Round 1
// baseline (584.511 us; speedup 1.0000x reference)
//
#include <hip/hip_runtime.h>
#include <hip/hip_bf16.h>
#include <math.h>

#define B_   4
#define T_   2048
#define V_   512
#define D_   256
#define H_   4
#define DH_  64
#define NB_  32
#define DFF_ 1024
#define NL_  2

typedef __attribute__((ext_vector_type(8))) short short8_t;
typedef __attribute__((ext_vector_type(4))) float float4_t;

#define MFMA16(a,b,c) __builtin_amdgcn_mfma_f32_16x16x32_bf16(a,b,c,0,0,0)

__device__ __forceinline__ unsigned short f2bf_bits(float f) {
    unsigned u = __float_as_uint(f);
    u += 0x7fffu + ((u >> 16) & 1u);
    return (unsigned short)(u >> 16);
}

// ---------------------------------------------------------------------------
// Weight transpose+cast: W[K][N] fp32 -> Wt[N][K] bf16. One 32x32 tile/block.
// ---------------------------------------------------------------------------
__global__ __launch_bounds__(256) void wt_kernel(
    const float* __restrict__ Wq, const float* __restrict__ Wk,
    const float* __restrict__ Wv, const float* __restrict__ Wo,
    const float* __restrict__ W1, const float* __restrict__ W2,
    const float* __restrict__ Wout,
    unsigned short* __restrict__ wqt, unsigned short* __restrict__ wkt,
    unsigned short* __restrict__ wvt, unsigned short* __restrict__ wot,
    unsigned short* __restrict__ w1t, unsigned short* __restrict__ w2t,
    unsigned short* __restrict__ woutt)
{
    __shared__ float tile[32][33];
    int bx = blockIdx.x, tid = threadIdx.x;
    const float* src; unsigned short* dst; int Kd, Nd, tr, tc;
    if (bx < 512) {                    // Wq/Wk/Wv/Wo, 2 layers each, 256x256
        int am = bx >> 6, t = bx & 63;
        const float* s4[4] = {Wq, Wk, Wv, Wo};
        unsigned short* d4[4] = {wqt, wkt, wvt, wot};
        src = s4[am >> 1] + (long)(am & 1) * 65536;
        dst = d4[am >> 1] + (long)(am & 1) * 65536;
        Kd = 256; Nd = 256; tr = t >> 3; tc = t & 7;
    } else if (bx < 1024) {            // W1: 2 x (256x1024)
        int idx = bx - 512, mat = idx >> 8, t = idx & 255;
        src = W1 + (long)mat * 262144; dst = w1t + (long)mat * 262144;
        Kd = 256; Nd = 1024; tr = t >> 5; tc = t & 31;
    } else if (bx < 1536) {            // W2: 2 x (1024x256)
        int idx = bx - 1024, mat = idx >> 8, t = idx & 255;
        src = W2 + (long)mat * 262144; dst = w2t + (long)mat * 262144;
        Kd = 1024; Nd = 256; tr = t >> 3; tc = t & 7;
    } else {                           // Wout: 256x512
        int t = bx - 1536;
        src = Wout; dst = woutt; Kd = 256; Nd = 512; tr = t >> 4; tc = t & 15;
    }
    int kr = tid >> 3, nc4 = (tid & 7) * 4;
    float4_t v = *(const float4_t*)&src[(long)(tr * 32 + kr) * Nd + tc * 32 + nc4];
    for (int j = 0; j < 4; ++j) tile[kr][nc4 + j] = v[j];
    __syncthreads();
    int nr = tid >> 3, kc4 = (tid & 7) * 4;
    unsigned short tmp[4];
    for (int j = 0; j < 4; ++j) tmp[j] = f2bf_bits(tile[kc4 + j][nr]);
    uint2 uu;
    uu.x = (unsigned)tmp[0] | ((unsigned)tmp[1] << 16);
    uu.y = (unsigned)tmp[2] | ((unsigned)tmp[3] << 16);
    *(uint2*)&dst[(long)(tc * 32 + nr) * Kd + tr * 32 + kc4] = uu;
}

// ---------------------------------------------------------------------------
// Token embedding gather + rank-2 delta projection
// ---------------------------------------------------------------------------
__global__ __launch_bounds__(256) void embed_kernel(
    const int* __restrict__ tokens, const float* __restrict__ emb,
    const float* __restrict__ w_in, const float* __restrict__ w_out,
    float* __restrict__ x, float* __restrict__ delta)
{
    int bt = blockIdx.x;
    int d  = threadIdx.x;
    int tok = tokens[bt];
    float e = emb[tok * D_ + d];
    x[(long)bt * D_ + d] = e;

    __shared__ float r0s[256], r1s[256];
    r0s[d] = e * w_in[d * 2 + 0];
    r1s[d] = e * w_in[d * 2 + 1];
    __syncthreads();
    for (int off = 128; off > 0; off >>= 1) {
        if (d < off) { r0s[d] += r0s[d + off]; r1s[d] += r1s[d + off]; }
        __syncthreads();
    }
    float r0 = r0s[0], r1 = r1s[0];
    if (d < H_ * NB_) {
        delta[(long)bt * (H_ * NB_) + d] =
            r0 * w_out[d] + r1 * w_out[H_ * NB_ + d];
    }
}

// ---------------------------------------------------------------------------
// cumsum over T per (b, channel) + cos/sin
// ---------------------------------------------------------------------------
__global__ __launch_bounds__(256) void cumsum_kernel(
    const float* __restrict__ delta, const float* __restrict__ omega,
    float* __restrict__ cosb, float* __restrict__ sinb)
{
    int c = blockIdx.x & (H_ * NB_ - 1);
    int b = blockIdx.x >> 7;
    int tid = threadIdx.x;
    float om = omega[c];
    int h = c >> 5, nb = c & (NB_ - 1);

    float vals[8];
    float s = 0.0f;
    for (int i = 0; i < 8; ++i) {
        int t = tid * 8 + i;
        vals[i] = delta[((long)b * T_ + t) * (H_ * NB_) + c];
        s += vals[i];
    }
    __shared__ float sc[256];
    sc[tid] = s;
    __syncthreads();
    for (int off = 1; off < 256; off <<= 1) {
        float v = (tid >= off) ? sc[tid - off] : 0.0f;
        __syncthreads();
        sc[tid] += v;
        __syncthreads();
    }
    float run = sc[tid] - s;
    for (int i = 0; i < 8; ++i) {
        run += vals[i];
        float ang = run * om;
        int t = tid * 8 + i;
        long oi = ((long)(b * H_ + h) * T_ + t) * NB_ + nb;
        cosb[oi] = cosf(ang);
        sinb[oi] = sinf(ang);
    }
}

// ---------------------------------------------------------------------------
// LayerNorm (fp32 in) -> bf16 out
// ---------------------------------------------------------------------------
__global__ __launch_bounds__(256) void ln_kernel(
    const float* __restrict__ x, const float* __restrict__ g,
    const float* __restrict__ b, unsigned short* __restrict__ out)
{
    int row = blockIdx.x;
    int d = threadIdx.x;
    float v = x[(long)row * D_ + d];
    __shared__ float ss[256], sq[256];
    ss[d] = v; sq[d] = v * v;
    __syncthreads();
    for (int off = 128; off > 0; off >>= 1) {
        if (d < off) { ss[d] += ss[d + off]; sq[d] += sq[d + off]; }
        __syncthreads();
    }
    float mu  = ss[0] * (1.0f / D_);
    float var = sq[0] * (1.0f / D_) - mu * mu;
    float inv = rsqrtf(var + 1e-5f);
    out[(long)row * D_ + d] = f2bf_bits((v - mu) * inv * g[d] + b[d]);
}

// ---------------------------------------------------------------------------
// MFMA GEMM: C[M,N] = A[M,K](bf16) @ Bt[N,K](bf16)^T + bias.
// 64x64 tile, BK=64, 4 waves x (16x64 strip), 16x16x32 MFMA.
// mode 0: fp32 out, row-major, bias per col, optional res add + gelu
// mode 1: bf16 out, row-major, bias per col, optional gelu
// mode 2: bf16 out, row-major, bias per ROW (for V^T via swapped operands)
// mode 3: bf16 out in (B,H,T,DH) layout with RoPE applied + qscale folded
// ---------------------------------------------------------------------------
__global__ __launch_bounds__(256) void gemm_mfma(
    const unsigned short* __restrict__ A, const unsigned short* __restrict__ Bt,
    const float* __restrict__ bias, const float* __restrict__ res,
    float* __restrict__ outf, unsigned short* __restrict__ outb,
    const float* __restrict__ ropeC, const float* __restrict__ ropeS,
    float qscale, int M, int N, int K, int mode, int do_gelu)
{
    __shared__ __align__(16) short As[64 * 72];
    __shared__ __align__(16) short Bs[64 * 72];
    int tid = threadIdx.x;
    int w = tid >> 6, lane = tid & 63, quad = lane >> 4, l16 = lane & 15;
    int n0 = blockIdx.x * 64, r0 = blockIdx.y * 64;

    float4_t acc[4];
    for (int nt = 0; nt < 4; ++nt) acc[nt] = (float4_t){0.f, 0.f, 0.f, 0.f};

    for (int k0 = 0; k0 < K; k0 += 64) {
        __syncthreads();
        for (int i = 0; i < 2; ++i) {
            int e = tid + 256 * i;
            int r = e >> 3, c8 = e & 7;
            *(short8_t*)&As[r * 72 + c8 * 8] =
                *(const short8_t*)&A[(long)(r0 + r) * K + k0 + c8 * 8];
            *(short8_t*)&Bs[r * 72 + c8 * 8] =
                *(const short8_t*)&Bt[(long)(n0 + r) * K + k0 + c8 * 8];
        }
        __syncthreads();
        for (int kq = 0; kq < 2; ++kq) {
            short8_t a = *(const short8_t*)&As[(w * 16 + l16) * 72 + kq * 32 + quad * 8];
            for (int nt = 0; nt < 4; ++nt) {
                short8_t bfr = *(const short8_t*)&Bs[(nt * 16 + l16) * 72 + kq * 32 + quad * 8];
                acc[nt] = MFMA16(a, bfr, acc[nt]);
            }
        }
    }

    int h_head = n0 >> 6;   // valid for mode 3 (N==256, tiles are head-aligned)
    for (int nt = 0; nt < 4; ++nt) {
        int n = n0 + nt * 16 + l16;
        float bcol = (mode == 2) ? 0.0f : bias[n];
        for (int r = 0; r < 4; ++r) {
            int row = r0 + w * 16 + quad * 4 + r;
            float v = acc[nt][r] + ((mode == 2) ? bias[row] : bcol);
            if (res) v += res[(long)row * N + n];
            if (do_gelu) v = 0.5f * v * (1.0f + erff(v * 0.70710678118654752f));
            if (mode == 0) {
                outf[(long)row * N + n] = v;
            } else if (mode == 1 || mode == 2) {
                outb[(long)row * N + n] = f2bf_bits(v);
            } else {  // mode 3: rope (pairs are adjacent columns -> lane^1)
                float vp = __shfl_xor(v, 1);
                int bb = row >> 11, t = row & (T_ - 1);
                int nb = (n & 63) >> 1;
                long ci = ((long)(bb * H_ + h_head) * T_ + t) * NB_ + nb;
                float c = ropeC[ci], sn = ropeS[ci];
                float ov = (l16 & 1) ? (vp * sn + v * c) : (v * c - vp * sn);
                outb[((long)(bb * H_ + h_head) * T_ + t) * DH_ + (n & 63)] =
                    f2bf_bits(ov * qscale);
            }
        }
    }
}

// ---------------------------------------------------------------------------
// MFMA flash attention, all-bf16 inputs, zero barriers.
// Q bf16 (B,H,T,DH) with rope+scale pre-applied -> A-frags (contiguous 16B).
// K bf16 (B,H,T,DH) with rope pre-applied -> B-frags direct from global.
// V^T bf16 [H*DH][B*T] -> PV B-frags direct from global (contiguous 16B).
// Softmax in-register; P via wave-private LDS strip (no __syncthreads).
// ---------------------------------------------------------------------------
__global__ __launch_bounds__(256) void attn_mfma(
    const unsigned short* __restrict__ Qb, const unsigned short* __restrict__ Kb,
    const unsigned short* __restrict__ Vt, unsigned short* __restrict__ O)
{
    __shared__ __align__(16) short Ps[4][16 * 72];

    int tid = threadIdx.x;
    int w = tid >> 6, lane = tid & 63;
    int quad = lane >> 4, l16 = lane & 15;
    int bh = blockIdx.x & 15;
    int qi = blockIdx.x >> 4;
    int qt = (qi < 16) ? qi : 47 - qi;   // pair qt with 31-qt for CU balance
    int q0 = qt * 64;
    int b = bh >> 2, h = bh & 3;

    // Q A-frags, held all kernel (scale 1/8 already folded in)
    const unsigned short* qp =
        Qb + ((long)bh * T_ + q0 + w * 16 + l16) * DH_ + quad * 8;
    short8_t aq[2];
    aq[0] = *(const short8_t*)qp;
    aq[1] = *(const short8_t*)(qp + 32);

    const unsigned short* kb_base = Kb + (long)bh * T_ * DH_ + quad * 8;
    const unsigned short* vt_base =
        Vt + (long)h * DH_ * (B_ * T_) + (long)b * T_ + quad * 8;

    float m_r[4], l_r[4];
    for (int r = 0; r < 4; ++r) { m_r[r] = -3.0e38f; l_r[r] = 0.0f; }
    float4_t o[4];
    for (int nt = 0; nt < 4; ++nt) o[nt] = (float4_t){0.f, 0.f, 0.f, 0.f};

    for (int kt = 0; kt <= qt; ++kt) {
        int k0 = kt * 64;

        // S = Q K^T, K B-frags straight from global (contiguous short8)
        float4_t s[4];
        for (int nt = 0; nt < 4; ++nt) {
            const unsigned short* kp = kb_base + (long)(k0 + nt * 16 + l16) * DH_;
            short8_t kf0 = *(const short8_t*)kp;
            short8_t kf1 = *(const short8_t*)(kp + 32);
            float4_t sa = (float4_t){0.f, 0.f, 0.f, 0.f};
            sa = MFMA16(aq[0], kf0, sa);
            sa = MFMA16(aq[1], kf1, sa);
            s[nt] = sa;
        }

        // causal mask + row max (C layout: row=quad*4+r, col=l16)
        bool diag = (kt == qt);
        float mt[4];
        for (int r = 0; r < 4; ++r) mt[r] = -3.0e38f;
        for (int nt = 0; nt < 4; ++nt) {
            int kcol = k0 + nt * 16 + l16;
            for (int r = 0; r < 4; ++r) {
                float sv = s[nt][r];
                if (diag && kcol > q0 + w * 16 + quad * 4 + r) sv = -3.0e38f;
                s[nt][r] = sv;
                mt[r] = fmaxf(mt[r], sv);
            }
        }
        for (int off = 1; off < 16; off <<= 1)
            for (int r = 0; r < 4; ++r)
                mt[r] = fmaxf(mt[r], __shfl_xor(mt[r], off));

        float alpha[4];
        for (int r = 0; r < 4; ++r) {
            float mn = fmaxf(m_r[r], mt[r]);
            alpha[r] = __expf(m_r[r] - mn);
            m_r[r] = mn;
        }

        float lt[4] = {0.f, 0.f, 0.f, 0.f};
        for (int nt = 0; nt < 4; ++nt) {
            for (int r = 0; r < 4; ++r) {
                float p = __expf(s[nt][r] - m_r[r]);
                lt[r] += p;
                Ps[w][(quad * 4 + r) * 72 + nt * 16 + l16] = (short)f2bf_bits(p);
            }
        }
        for (int off = 1; off < 16; off <<= 1)
            for (int r = 0; r < 4; ++r)
                lt[r] += __shfl_xor(lt[r], off);
        for (int r = 0; r < 4; ++r) l_r[r] = l_r[r] * alpha[r] + lt[r];
        for (int nt = 0; nt < 4; ++nt)
            for (int r = 0; r < 4; ++r) o[nt][r] *= alpha[r];

        // O += P @ V  (wave-private P strip; V^T frags contiguous short8)
        for (int kq = 0; kq < 2; ++kq) {
            short8_t pa = *(const short8_t*)&Ps[w][l16 * 72 + kq * 32 + quad * 8];
            for (int nt = 0; nt < 4; ++nt) {
                short8_t vb = *(const short8_t*)(
                    vt_base + (long)(nt * 16 + l16) * (B_ * T_) + k0 + kq * 32);
                o[nt] = MFMA16(pa, vb, o[nt]);
            }
        }
    }

    for (int r = 0; r < 4; ++r) {
        float inv = 1.0f / l_r[r];
        int trow = q0 + w * 16 + quad * 4 + r;
        long orow = ((long)b * T_ + trow) * D_ + h * 64;
        for (int nt = 0; nt < 4; ++nt)
            O[orow + nt * 16 + l16] = f2bf_bits(o[nt][r] * inv);
    }
}

// ---------------------------------------------------------------------------
extern "C" void kernel_launch(void* const* d_in, const int* in_sizes, int n_in,
                              void* d_out, int out_size, void* d_ws, size_t ws_size,
                              hipStream_t stream)
{
    const int*   tokens    = (const int*)d_in[0];
    const float* token_emb = (const float*)d_in[1];
    const float* w_in      = (const float*)d_in[2];
    const float* w_out     = (const float*)d_in[3];
    const float* omega     = (const float*)d_in[4];
    const float* Wq        = (const float*)d_in[5];
    const float* bq        = (const float*)d_in[6];
    const float* Wk        = (const float*)d_in[7];
    const float* bk        = (const float*)d_in[8];
    const float* Wv        = (const float*)d_in[9];
    const float* bv        = (const float*)d_in[10];
    const float* Wo        = (const float*)d_in[11];
    const float* bo        = (const float*)d_in[12];
    const float* ln1_g     = (const float*)d_in[13];
    const float* ln1_b     = (const float*)d_in[14];
    const float* ln2_g     = (const float*)d_in[15];
    const float* ln2_b     = (const float*)d_in[16];
    const float* W1        = (const float*)d_in[17];
    const float* b1        = (const float*)d_in[18];
    const float* W2        = (const float*)d_in[19];
    const float* b2        = (const float*)d_in[20];
    const float* out_g     = (const float*)d_in[21];
    const float* out_b     = (const float*)d_in[22];
    const float* Wout      = (const float*)d_in[23];
    const float* bout      = (const float*)d_in[24];

    const long NTOK = (long)B_ * T_;  // 8192
    float* xbuf = (float*)d_ws;                       // fp32 residual stream 8MB
    float* cosb = xbuf + NTOK * D_;                   // (B,H,T,NB) fp32 4MB
    float* sinb = cosb + NTOK * H_ * NB_;             // 4MB
    float* dbuf = sinb + NTOK * H_ * NB_;             // (B,T,H*NB) fp32 4MB
    unsigned short* hbuf  = (unsigned short*)(dbuf + NTOK * H_ * NB_); // bf16 LN out 4MB
    unsigned short* obuf  = hbuf + NTOK * D_;         // bf16 attn out 4MB
    unsigned short* ffbuf = obuf + NTOK * D_;         // bf16 FFN mid 16MB
    unsigned short* qb16  = ffbuf + NTOK * DFF_;      // bf16 Q (B,H,T,DH) 4MB
    unsigned short* kb16  = qb16 + NTOK * D_;         // bf16 K (B,H,T,DH) 4MB
    unsigned short* vtb   = kb16 + NTOK * D_;         // bf16 V^T [H*DH][B*T] 4MB
    unsigned short* wqt   = vtb + NTOK * D_;          // transposed bf16 weights
    unsigned short* wkt   = wqt + 2 * 65536;
    unsigned short* wvt   = wkt + 2 * 65536;
    unsigned short* wot   = wvt + 2 * 65536;
    unsigned short* w1t   = wot + 2 * 65536;
    unsigned short* w2t   = w1t + 2 * 262144;
    unsigned short* woutt = w2t + 2 * 262144;
    // total ~60 MB

    wt_kernel<<<1664, 256, 0, stream>>>(Wq, Wk, Wv, Wo, W1, W2, Wout,
                                        wqt, wkt, wvt, wot, w1t, w2t, woutt);
    embed_kernel<<<NTOK, 256, 0, stream>>>(tokens, token_emb, w_in, w_out, xbuf, dbuf);
    cumsum_kernel<<<B_ * H_ * NB_, 256, 0, stream>>>(dbuf, omega, cosb, sinb);

    for (int l = 0; l < NL_; ++l) {
        ln_kernel<<<NTOK, 256, 0, stream>>>(xbuf, ln1_g + l * D_, ln1_b + l * D_, hbuf);
        // Q: rope + 1/8 scale folded, bf16 attn layout
        gemm_mfma<<<dim3(4, 128), 256, 0, stream>>>(
            hbuf, wqt + (long)l * 65536, bq + l * D_, nullptr, nullptr, qb16,
            cosb, sinb, 0.125f, (int)NTOK, D_, D_, 3, 0);
        // K: rope folded, bf16 attn layout
        gemm_mfma<<<dim3(4, 128), 256, 0, stream>>>(
            hbuf, wkt + (long)l * 65536, bk + l * D_, nullptr, nullptr, kb16,
            cosb, sinb, 1.0f, (int)NTOK, D_, D_, 3, 0);
        // V^T via swapped operands: C[d][token] = sum_k Wv[k][d] h[token][k]
        gemm_mfma<<<dim3(128, 4), 256, 0, stream>>>(
            wvt + (long)l * 65536, hbuf, bv + l * D_, nullptr, nullptr, vtb,
            nullptr, nullptr, 0.f, D_, (int)NTOK, D_, 2, 0);
        attn_mfma<<<512, 256, 0, stream>>>(qb16, kb16, vtb, obuf);
        gemm_mfma<<<dim3(4, 128), 256, 0, stream>>>(
            obuf, wot + (long)l * 65536, bo + l * D_, xbuf, xbuf, nullptr,
            nullptr, nullptr, 0.f, (int)NTOK, D_, D_, 0, 0);
        ln_kernel<<<NTOK, 256, 0, stream>>>(xbuf, ln2_g + l * D_, ln2_b + l * D_, hbuf);
        gemm_mfma<<<dim3(16, 128), 256, 0, stream>>>(
            hbuf, w1t + (long)l * 262144, b1 + l * DFF_, nullptr, nullptr, ffbuf,
            nullptr, nullptr, 0.f, (int)NTOK, DFF_, D_, 1, 1);
        gemm_mfma<<<dim3(4, 128), 256, 0, stream>>>(
            ffbuf, w2t + (long)l * 262144, b2 + l * D_, xbuf, xbuf, nullptr,
            nullptr, nullptr, 0.f, (int)NTOK, D_, DFF_, 0, 0);
    }

    ln_kernel<<<NTOK, 256, 0, stream>>>(xbuf, out_g, out_b, hbuf);
    gemm_mfma<<<dim3(8, 128), 256, 0, stream>>>(
        hbuf, woutt, bout, nullptr, (float*)d_out, nullptr,
        nullptr, nullptr, 0.f, (int)NTOK, V_, D_, 0, 0);
}

// Round 2
// 519.175 us; speedup vs baseline: 1.1258x; 1.1258x over previous
//
#include <hip/hip_runtime.h>
#include <hip/hip_bf16.h>
#include <math.h>

#define B_   4
#define T_   2048
#define V_   512
#define D_   256
#define H_   4
#define DH_  64
#define NB_  32
#define DFF_ 1024
#define NL_  2

typedef __attribute__((ext_vector_type(8))) short short8_t;
typedef __attribute__((ext_vector_type(4))) float float4_t;

#define MFMA16(a,b,c) __builtin_amdgcn_mfma_f32_16x16x32_bf16(a,b,c,0,0,0)

__device__ __forceinline__ unsigned short f2bf_bits(float f) {
    unsigned u = __float_as_uint(f);
    u += 0x7fffu + ((u >> 16) & 1u);
    return (unsigned short)(u >> 16);
}

// ---------------------------------------------------------------------------
// Weight transpose+cast: W[K][N] fp32 -> Wt[N][K] bf16. One 32x32 tile/block.
// ---------------------------------------------------------------------------
__global__ __launch_bounds__(256) void wt_kernel(
    const float* __restrict__ Wq, const float* __restrict__ Wk,
    const float* __restrict__ Wv, const float* __restrict__ Wo,
    const float* __restrict__ W1, const float* __restrict__ W2,
    const float* __restrict__ Wout,
    unsigned short* __restrict__ wqt, unsigned short* __restrict__ wkt,
    unsigned short* __restrict__ wvt, unsigned short* __restrict__ wot,
    unsigned short* __restrict__ w1t, unsigned short* __restrict__ w2t,
    unsigned short* __restrict__ woutt)
{
    __shared__ float tile[32][33];
    int bx = blockIdx.x, tid = threadIdx.x;
    const float* src; unsigned short* dst; int Kd, Nd, tr, tc;
    if (bx < 512) {                    // Wq/Wk/Wv/Wo, 2 layers each, 256x256
        int am = bx >> 6, t = bx & 63;
        const float* s4[4] = {Wq, Wk, Wv, Wo};
        unsigned short* d4[4] = {wqt, wkt, wvt, wot};
        src = s4[am >> 1] + (long)(am & 1) * 65536;
        dst = d4[am >> 1] + (long)(am & 1) * 65536;
        Kd = 256; Nd = 256; tr = t >> 3; tc = t & 7;
    } else if (bx < 1024) {            // W1: 2 x (256x1024)
        int idx = bx - 512, mat = idx >> 8, t = idx & 255;
        src = W1 + (long)mat * 262144; dst = w1t + (long)mat * 262144;
        Kd = 256; Nd = 1024; tr = t >> 5; tc = t & 31;
    } else if (bx < 1536) {            // W2: 2 x (1024x256)
        int idx = bx - 1024, mat = idx >> 8, t = idx & 255;
        src = W2 + (long)mat * 262144; dst = w2t + (long)mat * 262144;
        Kd = 1024; Nd = 256; tr = t >> 3; tc = t & 7;
    } else {                           // Wout: 256x512
        int t = bx - 1536;
        src = Wout; dst = woutt; Kd = 256; Nd = 512; tr = t >> 4; tc = t & 15;
    }
    int kr = tid >> 3, nc4 = (tid & 7) * 4;
    float4_t v = *(const float4_t*)&src[(long)(tr * 32 + kr) * Nd + tc * 32 + nc4];
    for (int j = 0; j < 4; ++j) tile[kr][nc4 + j] = v[j];
    __syncthreads();
    int nr = tid >> 3, kc4 = (tid & 7) * 4;
    unsigned short tmp[4];
    for (int j = 0; j < 4; ++j) tmp[j] = f2bf_bits(tile[kc4 + j][nr]);
    uint2 uu;
    uu.x = (unsigned)tmp[0] | ((unsigned)tmp[1] << 16);
    uu.y = (unsigned)tmp[2] | ((unsigned)tmp[3] << 16);
    *(uint2*)&dst[(long)(tc * 32 + nr) * Kd + tr * 32 + kc4] = uu;
}

// ---------------------------------------------------------------------------
// Token embedding gather + rank-2 delta projection
// ---------------------------------------------------------------------------
__global__ __launch_bounds__(256) void embed_kernel(
    const int* __restrict__ tokens, const float* __restrict__ emb,
    const float* __restrict__ w_in, const float* __restrict__ w_out,
    float* __restrict__ x, float* __restrict__ delta)
{
    int bt = blockIdx.x;
    int d  = threadIdx.x;
    int tok = tokens[bt];
    float e = emb[tok * D_ + d];
    x[(long)bt * D_ + d] = e;

    __shared__ float r0s[256], r1s[256];
    r0s[d] = e * w_in[d * 2 + 0];
    r1s[d] = e * w_in[d * 2 + 1];
    __syncthreads();
    for (int off = 128; off > 0; off >>= 1) {
        if (d < off) { r0s[d] += r0s[d + off]; r1s[d] += r1s[d + off]; }
        __syncthreads();
    }
    float r0 = r0s[0], r1 = r1s[0];
    if (d < H_ * NB_) {
        delta[(long)bt * (H_ * NB_) + d] =
            r0 * w_out[d] + r1 * w_out[H_ * NB_ + d];
    }
}

// ---------------------------------------------------------------------------
// cumsum over T per (b, channel) + cos/sin
// ---------------------------------------------------------------------------
__global__ __launch_bounds__(256) void cumsum_kernel(
    const float* __restrict__ delta, const float* __restrict__ omega,
    float* __restrict__ cosb, float* __restrict__ sinb)
{
    int c = blockIdx.x & (H_ * NB_ - 1);
    int b = blockIdx.x >> 7;
    int tid = threadIdx.x;
    float om = omega[c];
    int h = c >> 5, nb = c & (NB_ - 1);

    float vals[8];
    float s = 0.0f;
    for (int i = 0; i < 8; ++i) {
        int t = tid * 8 + i;
        vals[i] = delta[((long)b * T_ + t) * (H_ * NB_) + c];
        s += vals[i];
    }
    __shared__ float sc[256];
    sc[tid] = s;
    __syncthreads();
    for (int off = 1; off < 256; off <<= 1) {
        float v = (tid >= off) ? sc[tid - off] : 0.0f;
        __syncthreads();
        sc[tid] += v;
        __syncthreads();
    }
    float run = sc[tid] - s;
    for (int i = 0; i < 8; ++i) {
        run += vals[i];
        float ang = run * om;
        int t = tid * 8 + i;
        long oi = ((long)(b * H_ + h) * T_ + t) * NB_ + nb;
        cosb[oi] = cosf(ang);
        sinb[oi] = sinf(ang);
    }
}

// ---------------------------------------------------------------------------
// LayerNorm (fp32 in) -> bf16 out
// ---------------------------------------------------------------------------
__global__ __launch_bounds__(256) void ln_kernel(
    const float* __restrict__ x, const float* __restrict__ g,
    const float* __restrict__ b, unsigned short* __restrict__ out)
{
    int row = blockIdx.x;
    int d = threadIdx.x;
    float v = x[(long)row * D_ + d];
    __shared__ float ss[256], sq[256];
    ss[d] = v; sq[d] = v * v;
    __syncthreads();
    for (int off = 128; off > 0; off >>= 1) {
        if (d < off) { ss[d] += ss[d + off]; sq[d] += sq[d + off]; }
        __syncthreads();
    }
    float mu  = ss[0] * (1.0f / D_);
    float var = sq[0] * (1.0f / D_) - mu * mu;
    float inv = rsqrtf(var + 1e-5f);
    out[(long)row * D_ + d] = f2bf_bits((v - mu) * inv * g[d] + b[d]);
}

// ---------------------------------------------------------------------------
// MFMA GEMM: C[M,N] = A[M,K](bf16) @ Bt[N,K](bf16)^T + bias.
// 64x64 tile, BK=64, 4 waves x (16x64 strip), 16x16x32 MFMA.
// mode 0: fp32 out, row-major, bias per col, optional res add + gelu
// mode 1: bf16 out, row-major, bias per col, optional gelu
// mode 2: bf16 out, row-major, bias per ROW (for V^T via swapped operands)
// mode 3: bf16 out in (B,H,T,DH) layout with RoPE applied + qscale folded
// ---------------------------------------------------------------------------
__global__ __launch_bounds__(256) void gemm_mfma(
    const unsigned short* __restrict__ A, const unsigned short* __restrict__ Bt,
    const float* __restrict__ bias, const float* __restrict__ res,
    float* __restrict__ outf, unsigned short* __restrict__ outb,
    const float* __restrict__ ropeC, const float* __restrict__ ropeS,
    float qscale, int M, int N, int K, int mode, int do_gelu)
{
    __shared__ __align__(16) short As[64 * 72];
    __shared__ __align__(16) short Bs[64 * 72];
    int tid = threadIdx.x;
    int w = tid >> 6, lane = tid & 63, quad = lane >> 4, l16 = lane & 15;
    int n0 = blockIdx.x * 64, r0 = blockIdx.y * 64;

    float4_t acc[4];
    for (int nt = 0; nt < 4; ++nt) acc[nt] = (float4_t){0.f, 0.f, 0.f, 0.f};

    for (int k0 = 0; k0 < K; k0 += 64) {
        __syncthreads();
        for (int i = 0; i < 2; ++i) {
            int e = tid + 256 * i;
            int r = e >> 3, c8 = e & 7;
            *(short8_t*)&As[r * 72 + c8 * 8] =
                *(const short8_t*)&A[(long)(r0 + r) * K + k0 + c8 * 8];
            *(short8_t*)&Bs[r * 72 + c8 * 8] =
                *(const short8_t*)&Bt[(long)(n0 + r) * K + k0 + c8 * 8];
        }
        __syncthreads();
        for (int kq = 0; kq < 2; ++kq) {
            short8_t a = *(const short8_t*)&As[(w * 16 + l16) * 72 + kq * 32 + quad * 8];
            for (int nt = 0; nt < 4; ++nt) {
                short8_t bfr = *(const short8_t*)&Bs[(nt * 16 + l16) * 72 + kq * 32 + quad * 8];
                acc[nt] = MFMA16(a, bfr, acc[nt]);
            }
        }
    }

    int h_head = n0 >> 6;   // valid for mode 3 (N==256, tiles are head-aligned)
    for (int nt = 0; nt < 4; ++nt) {
        int n = n0 + nt * 16 + l16;
        float bcol = (mode == 2) ? 0.0f : bias[n];
        for (int r = 0; r < 4; ++r) {
            int row = r0 + w * 16 + quad * 4 + r;
            float v = acc[nt][r] + ((mode == 2) ? bias[row] : bcol);
            if (res) v += res[(long)row * N + n];
            if (do_gelu) v = 0.5f * v * (1.0f + erff(v * 0.70710678118654752f));
            if (mode == 0) {
                outf[(long)row * N + n] = v;
            } else if (mode == 1 || mode == 2) {
                outb[(long)row * N + n] = f2bf_bits(v);
            } else {  // mode 3: rope (pairs are adjacent columns -> lane^1)
                float vp = __shfl_xor(v, 1);
                int bb = row >> 11, t = row & (T_ - 1);
                int nb = (n & 63) >> 1;
                long ci = ((long)(bb * H_ + h_head) * T_ + t) * NB_ + nb;
                float c = ropeC[ci], sn = ropeS[ci];
                float ov = (l16 & 1) ? (vp * sn + v * c) : (v * c - vp * sn);
                outb[((long)(bb * H_ + h_head) * T_ + t) * DH_ + (n & 63)] =
                    f2bf_bits(ov * qscale);
            }
        }
    }
}

// ---------------------------------------------------------------------------
// MFMA flash attention, all-bf16 inputs, zero barriers.
// 8 waves/block: waves 0-3 handle q-tile p, waves 4-7 handle q-tile 31-p.
// Waves w and w+4 share a SIMD -> per-SIMD work = (p+1)+(32-p) = 33 k-tiles,
// uniform across all 256 blocks = 256 CUs. No load-imbalance tail.
// K fragments software-pipelined (prefetch kt+1 during softmax of kt);
// V fragments issued at iteration top, consumed after softmax.
// Q bf16 (B,H,T,DH) rope+scale pre-applied; K bf16 same layout; V^T bf16.
// Softmax in-register; P via wave-private LDS strip (no __syncthreads).
// ---------------------------------------------------------------------------
__global__ __launch_bounds__(512) void attn_mfma(
    const unsigned short* __restrict__ Qb, const unsigned short* __restrict__ Kb,
    const unsigned short* __restrict__ Vt, unsigned short* __restrict__ O)
{
    __shared__ __align__(16) short Ps[8][16 * 72];

    int tid = threadIdx.x;
    int w = tid >> 6, lane = tid & 63;
    int quad = lane >> 4, l16 = lane & 15;
    int bh = blockIdx.x & 15;
    int p  = blockIdx.x >> 4;            // 0..15
    int qt = (w < 4) ? p : 31 - p;       // heavy+light share each SIMD
    int wr = w & 3;                      // 16-row group within the 64-row tile
    int q0 = qt * 64;
    int b = bh >> 2, h = bh & 3;

    // Q A-frags, held all kernel (scale 1/8 already folded in)
    const unsigned short* qp =
        Qb + ((long)bh * T_ + q0 + wr * 16 + l16) * DH_ + quad * 8;
    short8_t aq[2];
    aq[0] = *(const short8_t*)qp;
    aq[1] = *(const short8_t*)(qp + 32);

    const unsigned short* kb_base = Kb + (long)bh * T_ * DH_ + quad * 8;
    const unsigned short* vt_base =
        Vt + (long)h * DH_ * (B_ * T_) + (long)b * T_ + quad * 8;

    float m_r[4], l_r[4];
    for (int r = 0; r < 4; ++r) { m_r[r] = -3.0e38f; l_r[r] = 0.0f; }
    float4_t o[4];
    for (int nt = 0; nt < 4; ++nt) o[nt] = (float4_t){0.f, 0.f, 0.f, 0.f};

    // prefetch K fragments for kt=0
    short8_t kf[4][2];
    for (int nt = 0; nt < 4; ++nt) {
        const unsigned short* kp = kb_base + (long)(nt * 16 + l16) * DH_;
        kf[nt][0] = *(const short8_t*)kp;
        kf[nt][1] = *(const short8_t*)(kp + 32);
    }

    for (int kt = 0; kt <= qt; ++kt) {
        int k0 = kt * 64;

        // V fragments for this tile: issue early, consume after softmax
        short8_t vb[4][2];
        for (int nt = 0; nt < 4; ++nt)
            for (int kq = 0; kq < 2; ++kq)
                vb[nt][kq] = *(const short8_t*)(
                    vt_base + (long)(nt * 16 + l16) * (B_ * T_) + k0 + kq * 32);

        // S = Q K^T from prefetched K fragments (no memory wait)
        float4_t s[4];
        for (int nt = 0; nt < 4; ++nt) {
            float4_t sa = (float4_t){0.f, 0.f, 0.f, 0.f};
            sa = MFMA16(aq[0], kf[nt][0], sa);
            sa = MFMA16(aq[1], kf[nt][1], sa);
            s[nt] = sa;
        }

        // prefetch K fragments for kt+1 (hidden under softmax)
        if (kt < qt) {
            for (int nt = 0; nt < 4; ++nt) {
                const unsigned short* kp =
                    kb_base + (long)(k0 + 64 + nt * 16 + l16) * DH_;
                kf[nt][0] = *(const short8_t*)kp;
                kf[nt][1] = *(const short8_t*)(kp + 32);
            }
        }

        // causal mask + row max (C layout: row=quad*4+r, col=l16)
        bool diag = (kt == qt);
        float mt[4];
        for (int r = 0; r < 4; ++r) mt[r] = -3.0e38f;
        for (int nt = 0; nt < 4; ++nt) {
            int kcol = k0 + nt * 16 + l16;
            for (int r = 0; r < 4; ++r) {
                float sv = s[nt][r];
                if (diag && kcol > q0 + wr * 16 + quad * 4 + r) sv = -3.0e38f;
                s[nt][r] = sv;
                mt[r] = fmaxf(mt[r], sv);
            }
        }
        for (int off = 1; off < 16; off <<= 1)
            for (int r = 0; r < 4; ++r)
                mt[r] = fmaxf(mt[r], __shfl_xor(mt[r], off));

        float alpha[4];
        for (int r = 0; r < 4; ++r) {
            float mn = fmaxf(m_r[r], mt[r]);
            alpha[r] = __expf(m_r[r] - mn);
            m_r[r] = mn;
        }

        float lt[4] = {0.f, 0.f, 0.f, 0.f};
        for (int nt = 0; nt < 4; ++nt) {
            for (int r = 0; r < 4; ++r) {
                float pv = __expf(s[nt][r] - m_r[r]);
                lt[r] += pv;
                Ps[w][(quad * 4 + r) * 72 + nt * 16 + l16] = (short)f2bf_bits(pv);
            }
        }
        for (int off = 1; off < 16; off <<= 1)
            for (int r = 0; r < 4; ++r)
                lt[r] += __shfl_xor(lt[r], off);
        for (int r = 0; r < 4; ++r) l_r[r] = l_r[r] * alpha[r] + lt[r];
        for (int nt = 0; nt < 4; ++nt)
            for (int r = 0; r < 4; ++r) o[nt][r] *= alpha[r];

        // O += P @ V  (wave-private P strip; V^T frags contiguous short8)
        for (int kq = 0; kq < 2; ++kq) {
            short8_t pa = *(const short8_t*)&Ps[w][l16 * 72 + kq * 32 + quad * 8];
            for (int nt = 0; nt < 4; ++nt)
                o[nt] = MFMA16(pa, vb[nt][kq], o[nt]);
        }
    }

    for (int r = 0; r < 4; ++r) {
        float inv = 1.0f / l_r[r];
        int trow = q0 + wr * 16 + quad * 4 + r;
        long orow = ((long)b * T_ + trow) * D_ + h * 64;
        for (int nt = 0; nt < 4; ++nt)
            O[orow + nt * 16 + l16] = f2bf_bits(o[nt][r] * inv);
    }
}

// ---------------------------------------------------------------------------
extern "C" void kernel_launch(void* const* d_in, const int* in_sizes, int n_in,
                              void* d_out, int out_size, void* d_ws, size_t ws_size,
                              hipStream_t stream)
{
    const int*   tokens    = (const int*)d_in[0];
    const float* token_emb = (const float*)d_in[1];
    const float* w_in      = (const float*)d_in[2];
    const float* w_out     = (const float*)d_in[3];
    const float* omega     = (const float*)d_in[4];
    const float* Wq        = (const float*)d_in[5];
    const float* bq        = (const float*)d_in[6];
    const float* Wk        = (const float*)d_in[7];
    const float* bk        = (const float*)d_in[8];
    const float* Wv        = (const float*)d_in[9];
    const float* bv        = (const float*)d_in[10];
    const float* Wo        = (const float*)d_in[11];
    const float* bo        = (const float*)d_in[12];
    const float* ln1_g     = (const float*)d_in[13];
    const float* ln1_b     = (const float*)d_in[14];
    const float* ln2_g     = (const float*)d_in[15];
    const float* ln2_b     = (const float*)d_in[16];
    const float* W1        = (const float*)d_in[17];
    const float* b1        = (const float*)d_in[18];
    const float* W2        = (const float*)d_in[19];
    const float* b2        = (const float*)d_in[20];
    const float* out_g     = (const float*)d_in[21];
    const float* out_b     = (const float*)d_in[22];
    const float* Wout      = (const float*)d_in[23];
    const float* bout      = (const float*)d_in[24];

    const long NTOK = (long)B_ * T_;  // 8192
    float* xbuf = (float*)d_ws;                       // fp32 residual stream 8MB
    float* cosb = xbuf + NTOK * D_;                   // (B,H,T,NB) fp32 4MB
    float* sinb = cosb + NTOK * H_ * NB_;             // 4MB
    float* dbuf = sinb + NTOK * H_ * NB_;             // (B,T,H*NB) fp32 4MB
    unsigned short* hbuf  = (unsigned short*)(dbuf + NTOK * H_ * NB_); // bf16 LN out 4MB
    unsigned short* obuf  = hbuf + NTOK * D_;         // bf16 attn out 4MB
    unsigned short* ffbuf = obuf + NTOK * D_;         // bf16 FFN mid 16MB
    unsigned short* qb16  = ffbuf + NTOK * DFF_;      // bf16 Q (B,H,T,DH) 4MB
    unsigned short* kb16  = qb16 + NTOK * D_;         // bf16 K (B,H,T,DH) 4MB
    unsigned short* vtb   = kb16 + NTOK * D_;         // bf16 V^T [H*DH][B*T] 4MB
    unsigned short* wqt   = vtb + NTOK * D_;          // transposed bf16 weights
    unsigned short* wkt   = wqt + 2 * 65536;
    unsigned short* wvt   = wkt + 2 * 65536;
    unsigned short* wot   = wvt + 2 * 65536;
    unsigned short* w1t   = wot + 2 * 65536;
    unsigned short* w2t   = w1t + 2 * 262144;
    unsigned short* woutt = w2t + 2 * 262144;
    // total ~60 MB

    wt_kernel<<<1664, 256, 0, stream>>>(Wq, Wk, Wv, Wo, W1, W2, Wout,
                                        wqt, wkt, wvt, wot, w1t, w2t, woutt);
    embed_kernel<<<NTOK, 256, 0, stream>>>(tokens, token_emb, w_in, w_out, xbuf, dbuf);
    cumsum_kernel<<<B_ * H_ * NB_, 256, 0, stream>>>(dbuf, omega, cosb, sinb);

    for (int l = 0; l < NL_; ++l) {
        ln_kernel<<<NTOK, 256, 0, stream>>>(xbuf, ln1_g + l * D_, ln1_b + l * D_, hbuf);
        // Q: rope + 1/8 scale folded, bf16 attn layout
        gemm_mfma<<<dim3(4, 128), 256, 0, stream>>>(
            hbuf, wqt + (long)l * 65536, bq + l * D_, nullptr, nullptr, qb16,
            cosb, sinb, 0.125f, (int)NTOK, D_, D_, 3, 0);
        // K: rope folded, bf16 attn layout
        gemm_mfma<<<dim3(4, 128), 256, 0, stream>>>(
            hbuf, wkt + (long)l * 65536, bk + l * D_, nullptr, nullptr, kb16,
            cosb, sinb, 1.0f, (int)NTOK, D_, D_, 3, 0);
        // V^T via swapped operands: C[d][token] = sum_k Wv[k][d] h[token][k]
        gemm_mfma<<<dim3(128, 4), 256, 0, stream>>>(
            wvt + (long)l * 65536, hbuf, bv + l * D_, nullptr, nullptr, vtb,
            nullptr, nullptr, 0.f, D_, (int)NTOK, D_, 2, 0);
        attn_mfma<<<256, 512, 0, stream>>>(qb16, kb16, vtb, obuf);
        gemm_mfma<<<dim3(4, 128), 256, 0, stream>>>(
            obuf, wot + (long)l * 65536, bo + l * D_, xbuf, xbuf, nullptr,
            nullptr, nullptr, 0.f, (int)NTOK, D_, D_, 0, 0);
        ln_kernel<<<NTOK, 256, 0, stream>>>(xbuf, ln2_g + l * D_, ln2_b + l * D_, hbuf);
        gemm_mfma<<<dim3(16, 128), 256, 0, stream>>>(
            hbuf, w1t + (long)l * 262144, b1 + l * DFF_, nullptr, nullptr, ffbuf,
            nullptr, nullptr, 0.f, (int)NTOK, DFF_, D_, 1, 1);
        gemm_mfma<<<dim3(4, 128), 256, 0, stream>>>(
            ffbuf, w2t + (long)l * 262144, b2 + l * D_, xbuf, xbuf, nullptr,
            nullptr, nullptr, 0.f, (int)NTOK, D_, DFF_, 0, 0);
    }

    ln_kernel<<<NTOK, 256, 0, stream>>>(xbuf, out_g, out_b, hbuf);
    gemm_mfma<<<dim3(8, 128), 256, 0, stream>>>(
        hbuf, woutt, bout, nullptr, (float*)d_out, nullptr,
        nullptr, nullptr, 0.f, (int)NTOK, V_, D_, 0, 0);
}